// Round 1
// baseline (1570.286 us; speedup 1.0000x reference)
//
#include <hip/hip_runtime.h>
#include <math.h>

// Problem constants
constexpr int B_ = 512;
constexpr int T_ = 128;
constexpr int D_ = 128;   // d_model
constexpr int H_ = 6;     // heads
constexpr int E_ = 21;    // d_head
constexpr int DC_ = 126;  // concat dim (H*E)
constexpr int F_ = 512;   // d_ff
constexpr float EPS_ = 1e-5f;

// ---------------- Kernel 1: LayerNorm (x -> h), one 128-thread block per row ----------------
__global__ __launch_bounds__(128) void ln_kernel(const float* __restrict__ x,
                                                 const float* __restrict__ g,
                                                 const float* __restrict__ b,
                                                 float* __restrict__ out) {
    int row = blockIdx.x;
    int d = threadIdx.x;
    float v = x[(size_t)row * D_ + d];
    float sum = v, sq = v * v;
    #pragma unroll
    for (int off = 32; off >= 1; off >>= 1) {
        sum += __shfl_down(sum, off);
        sq  += __shfl_down(sq, off);
    }
    __shared__ float s1[2], s2[2];
    int wave = d >> 6, lane = d & 63;
    if (lane == 0) { s1[wave] = sum; s2[wave] = sq; }
    __syncthreads();
    float tsum = s1[0] + s1[1];
    float tsq  = s2[0] + s2[1];
    float mu = tsum * (1.0f / D_);
    float var = tsq * (1.0f / D_) - mu * mu;
    float rs = rsqrtf(var + EPS_);
    out[(size_t)row * D_ + d] = (v - mu) * rs * g[d] + b[d];
}

// ---------------- Kernel 2: QKV projection, one block per (head, batch) ----------------
__global__ __launch_bounds__(256) void qkv_kernel(const float* __restrict__ h1,
                                                  const float* __restrict__ Wq,
                                                  const float* __restrict__ Wk,
                                                  const float* __restrict__ Wv,
                                                  float* __restrict__ q,
                                                  float* __restrict__ k,
                                                  float* __restrict__ v) {
    int hd = blockIdx.x;  // head
    int b  = blockIdx.y;  // batch
    __shared__ float sh[T_][D_];       // 64 KiB
    __shared__ float sw[3][D_][E_];    // 31.5 KiB
    int tid = threadIdx.x;
    for (int i = tid; i < T_ * D_; i += 256)
        sh[i / D_][i % D_] = h1[((size_t)b * T_) * D_ + i];
    const float* wsrc[3] = {Wq, Wk, Wv};
    #pragma unroll
    for (int w = 0; w < 3; ++w)
        for (int i = tid; i < D_ * E_; i += 256)
            sw[w][i / E_][i % E_] = wsrc[w][(size_t)hd * D_ * E_ + i];
    __syncthreads();
    // 128 t * 63 outputs (3*21) = 8064 = 32 * 252
    for (int p = 0; p < 32; ++p) {
        if (tid < 252) {
            int idx = p * 252 + tid;
            int t = idx / 63, o = idx % 63;
            int w = o / E_, e = o % E_;
            float acc = 0.f;
            #pragma unroll 8
            for (int d0 = 0; d0 < D_; ++d0) acc += sh[t][d0] * sw[w][d0][e];
            size_t oi = (((size_t)b * H_ + hd) * T_ + t) * E_ + e;
            (w == 0 ? q : (w == 1 ? k : v))[oi] = acc;
        }
    }
}

// ---------------- Kernel 3: attention per (head, batch) ----------------
__global__ __launch_bounds__(256) void attn_kernel(const float* __restrict__ q,
                                                   const float* __restrict__ k,
                                                   const float* __restrict__ v,
                                                   float* __restrict__ o) {
    int hd = blockIdx.x;
    int b  = blockIdx.y;
    __shared__ float sq[T_][E_], sk[T_][E_], sv[T_][E_];  // 31.5 KiB
    __shared__ float sc[T_][T_ + 1];                      // 64.5 KiB (padded vs bank conflicts)
    int tid = threadIdx.x;
    size_t base = ((size_t)b * H_ + hd) * T_ * E_;
    for (int i = tid; i < T_ * E_; i += 256) {
        sq[i / E_][i % E_] = q[base + i];
        sk[i / E_][i % E_] = k[base + i];
        sv[i / E_][i % E_] = v[base + i];
    }
    __syncthreads();
    const float scale = 0.21821789023599236f;  // 1/sqrt(21)
    {
        int t = tid >> 1, half = tid & 1;
        for (int s = half; s <= t; s += 2) {
            float acc = 0.f;
            #pragma unroll
            for (int e = 0; e < E_; ++e) acc += sq[t][e] * sk[s][e];
            sc[t][s] = acc * scale;
        }
    }
    __syncthreads();
    if (tid < T_) {
        int t = tid;
        float m = -1e30f;
        for (int s = 0; s <= t; ++s) m = fmaxf(m, sc[t][s]);
        float sum = 0.f;
        for (int s = 0; s <= t; ++s) { float e2 = expf(sc[t][s] - m); sc[t][s] = e2; sum += e2; }
        float inv = 1.0f / sum;
        for (int s = 0; s <= t; ++s) sc[t][s] *= inv;
    }
    __syncthreads();
    // o[t][e] = sum_{s<=t} a[t][s] * v[s][e]; 2688 outputs
    for (int p = 0; p < 11; ++p) {
        int idx = p * 256 + tid;
        if (idx < T_ * E_) {
            int t = idx / E_, e = idx % E_;
            float acc = 0.f;
            for (int s = 0; s <= t; ++s) acc += sc[t][s] * sv[s][e];
            o[((size_t)b * T_ + t) * DC_ + hd * E_ + e] = acc;
        }
    }
}

// ---------------- Kernel 4: x2 = x + o @ Wo + bo, 8 rows per 256-thread block ----------------
__global__ __launch_bounds__(256) void proj_kernel(const float* __restrict__ x,
                                                   const float* __restrict__ o,
                                                   const float* __restrict__ Wo,
                                                   const float* __restrict__ bo,
                                                   float* __restrict__ x2) {
    int r0 = blockIdx.x * 8;
    __shared__ float so[8][DC_];
    int tid = threadIdx.x;
    for (int i = tid; i < 8 * DC_; i += 256) so[i / DC_][i % DC_] = o[(size_t)r0 * DC_ + i];
    __syncthreads();
    int d = tid & 127, half = tid >> 7;  // each 128-thread group handles 4 rows
    float acc[4] = {0.f, 0.f, 0.f, 0.f};
    for (int c = 0; c < DC_; ++c) {
        float w = Wo[(size_t)c * D_ + d];
        #pragma unroll
        for (int r = 0; r < 4; ++r) acc[r] += so[half * 4 + r][c] * w;
    }
    #pragma unroll
    for (int r = 0; r < 4; ++r) {
        size_t row = r0 + half * 4 + r;
        x2[row * D_ + d] = x[row * D_ + d] + bo[d] + acc[r];
    }
}

// ---------------- Kernel 5: fused LN2 + FF1 + ReLU + FF2 + residual, in place on x2 ----------------
__global__ __launch_bounds__(256) void ff_kernel(float* __restrict__ xio,
                                                 const float* __restrict__ g2,
                                                 const float* __restrict__ be2,
                                                 const float* __restrict__ W1,
                                                 const float* __restrict__ b1,
                                                 const float* __restrict__ W2,
                                                 const float* __restrict__ b2) {
    constexpr int R = 16;
    int r0 = blockIdx.x * R;
    __shared__ float xr[R][D_];   // 8 KiB
    __shared__ float h2[R][D_];   // 8 KiB (reused as partial buffer in FF2)
    __shared__ float ff[R][F_];   // 32 KiB
    __shared__ float smu[R], srs[R];
    int tid = threadIdx.x;
    for (int i = tid; i < R * D_; i += 256) xr[i / D_][i % D_] = xio[(size_t)r0 * D_ + i];
    __syncthreads();
    // LayerNorm: 16 threads per row
    {
        int r = tid >> 4, l = tid & 15;
        float sum = 0.f, sq = 0.f;
        for (int d0 = l; d0 < D_; d0 += 16) { float vv = xr[r][d0]; sum += vv; sq += vv * vv; }
        #pragma unroll
        for (int off = 8; off >= 1; off >>= 1) {
            sum += __shfl_down(sum, off, 16);
            sq  += __shfl_down(sq, off, 16);
        }
        if (l == 0) {
            float mu = sum * (1.0f / D_);
            smu[r] = mu;
            srs[r] = rsqrtf(sq * (1.0f / D_) - mu * mu + EPS_);
        }
    }
    __syncthreads();
    for (int i = tid; i < R * D_; i += 256) {
        int r = i / D_, d0 = i % D_;
        h2[r][d0] = (xr[r][d0] - smu[r]) * srs[r] * g2[d0] + be2[d0];
    }
    __syncthreads();
    // FF1: each thread computes columns tid and tid+256 for all 16 rows
    {
        float acc0[R], acc1[R];
        #pragma unroll
        for (int r = 0; r < R; ++r) { acc0[r] = 0.f; acc1[r] = 0.f; }
        int j0 = tid, j1 = tid + 256;
        for (int d0 = 0; d0 < D_; ++d0) {
            float w0 = W1[(size_t)d0 * F_ + j0];
            float w1 = W1[(size_t)d0 * F_ + j1];
            #pragma unroll
            for (int r = 0; r < R; ++r) {
                float hv = h2[r][d0];
                acc0[r] += hv * w0;
                acc1[r] += hv * w1;
            }
        }
        float bb0 = b1[j0], bb1 = b1[j1];
        #pragma unroll
        for (int r = 0; r < R; ++r) {
            ff[r][j0] = fmaxf(acc0[r] + bb0, 0.f);
            ff[r][j1] = fmaxf(acc1[r] + bb1, 0.f);
        }
    }
    __syncthreads();
    // FF2: 2 j-partitions x 128 d; partial sums combined through h2 (safe to reuse)
    {
        int d0 = tid & 127, p = tid >> 7;
        float acc[R];
        #pragma unroll
        for (int r = 0; r < R; ++r) acc[r] = 0.f;
        for (int j = p * 256; j < p * 256 + 256; ++j) {
            float w = W2[(size_t)j * D_ + d0];
            #pragma unroll
            for (int r = 0; r < R; ++r) acc[r] += ff[r][j] * w;
        }
        if (p == 1) {
            #pragma unroll
            for (int r = 0; r < R; ++r) h2[r][d0] = acc[r];
        }
        __syncthreads();
        if (p == 0) {
            #pragma unroll
            for (int r = 0; r < R; ++r) {
                float res = xr[r][d0] + b2[d0] + acc[r] + h2[r][d0];
                xio[(size_t)(r0 + r) * D_ + d0] = res;
            }
        }
    }
}

extern "C" void kernel_launch(void* const* d_in, const int* in_sizes, int n_in,
                              void* d_out, int out_size, void* d_ws, size_t ws_size,
                              hipStream_t stream) {
    const float* x   = (const float*)d_in[0];
    const float* Wq  = (const float*)d_in[1];
    const float* Wk  = (const float*)d_in[2];
    const float* Wv  = (const float*)d_in[3];
    const float* Wo  = (const float*)d_in[4];
    const float* bo  = (const float*)d_in[5];
    const float* W1  = (const float*)d_in[6];
    const float* b1  = (const float*)d_in[7];
    const float* W2  = (const float*)d_in[8];
    const float* b2  = (const float*)d_in[9];
    const float* g1  = (const float*)d_in[10];
    const float* be1 = (const float*)d_in[11];
    const float* g2  = (const float*)d_in[12];
    const float* be2 = (const float*)d_in[13];
    float* out = (float*)d_out;

    // Workspace: q, k, v (B,H,T,E) and o (B,T,DC) — 132 MB total, fully rewritten each call.
    size_t qkv_sz = (size_t)B_ * H_ * T_ * E_;
    float* q = (float*)d_ws;
    float* k = q + qkv_sz;
    float* v = k + qkv_sz;
    float* o = v + qkv_sz;

    // h1 (LN1 output) is staged in d_out, consumed by qkv, then overwritten by proj.
    ln_kernel<<<B_ * T_, 128, 0, stream>>>(x, g1, be1, out);
    qkv_kernel<<<dim3(H_, B_), 256, 0, stream>>>(out, Wq, Wk, Wv, q, k, v);
    attn_kernel<<<dim3(H_, B_), 256, 0, stream>>>(q, k, v, o);
    proj_kernel<<<B_ * T_ / 8, 256, 0, stream>>>(x, o, Wo, bo, out);
    ff_kernel<<<B_ * T_ / 16, 256, 0, stream>>>(out, g2, be2, W1, b1, W2, b2);
}

// Round 2
// 363.083 us; speedup vs baseline: 4.3249x; 4.3249x over previous
//
#include <hip/hip_runtime.h>
#include <math.h>

typedef short short8 __attribute__((ext_vector_type(8)));
typedef float f32x4 __attribute__((ext_vector_type(4)));

constexpr int B_ = 512, T_ = 128, D_ = 128, H_ = 6, E_ = 21, DC_ = 126, F_ = 512;
constexpr float EPS_ = 1e-5f;

__device__ __forceinline__ short f2bf(float f) {
    unsigned u = __float_as_uint(f);
    u = (u + 0x7FFFu + ((u >> 16) & 1u)) >> 16;
    return (short)u;
}
__device__ __forceinline__ f32x4 mfma16(short8 a, short8 b, f32x4 c) {
    return __builtin_amdgcn_mfma_f32_16x16x32_bf16(a, b, c, 0, 0, 0);
}

// ---------------- prep: bf16-cast + transpose all weights into ws ----------------
// WcatT[384][128]: n=(w*6+head)*21+e (378 used, rest 0), k = d_model
// W1T[512][128], W2T[128][512], WoT[128][128] (c>=126 zero-padded)
__global__ __launch_bounds__(256) void prep_kernel(
    const float* __restrict__ Wq, const float* __restrict__ Wk, const float* __restrict__ Wv,
    const float* __restrict__ Wo, const float* __restrict__ W1, const float* __restrict__ W2,
    short* __restrict__ WcatT, short* __restrict__ W1T, short* __restrict__ W2T,
    short* __restrict__ WoT) {
    int idx = blockIdx.x * 256 + threadIdx.x;
    if (idx < 49152) {
        int n = idx >> 7, k = idx & 127;
        float v = 0.f;
        if (n < 378) {
            int w = n / 126, r = n % 126, hd = r / 21, e = r % 21;
            const float* src = (w == 0) ? Wq : (w == 1) ? Wk : Wv;
            v = src[(hd * 128 + k) * 21 + e];
        }
        WcatT[idx] = f2bf(v);
    } else if (idx < 114688) {
        int i = idx - 49152;
        int j = i >> 7, d = i & 127;
        W1T[i] = f2bf(W1[d * 512 + j]);
    } else if (idx < 180224) {
        int i = idx - 114688;
        int d = i >> 9, j = i & 511;
        W2T[i] = f2bf(W2[j * 128 + d]);
    } else if (idx < 196608) {
        int i = idx - 180224;
        int d = i >> 7, c = i & 127;
        WoT[i] = f2bf(c < 126 ? Wo[c * 128 + d] : 0.f);
    }
}

// ---------------- fused LN1 + QKV MFMA: one block per batch b ----------------
// Writes Qg/Kg bf16 [b][h][128][32] (e>=21 left unwritten, masked downstream)
// and VTg bf16 [b][h][32][128] (rows e>=21 unwritten).
__global__ __launch_bounds__(512) void qkv_kernel(
    const float* __restrict__ x, const float* __restrict__ g1, const float* __restrict__ be1,
    const short* __restrict__ WcatT,
    short* __restrict__ Qg, short* __restrict__ Kg, short* __restrict__ VTg) {
    __shared__ __align__(16) short hA[T_ * D_];  // bf16 [128][128], swz ^((row&7)<<4)
    int b = blockIdx.x, tid = threadIdx.x;
    const short8 szero = {0, 0, 0, 0, 0, 0, 0, 0};
    const f32x4 fzero = {0.f, 0.f, 0.f, 0.f};
    (void)szero;
    {   // LN1: 4 threads per row, 128 rows
        int r = tid >> 2, q = tid & 3;
        const float* xr = x + ((size_t)b * T_ + r) * D_ + q * 32;
        float vals[32];
        float sum = 0.f, sq = 0.f;
        #pragma unroll
        for (int i = 0; i < 8; ++i) {
            f32x4 v4 = *(const f32x4*)(xr + i * 4);
            #pragma unroll
            for (int j = 0; j < 4; ++j) { float vv = v4[j]; vals[i*4+j] = vv; sum += vv; sq += vv*vv; }
        }
        sum += __shfl_xor(sum, 1); sum += __shfl_xor(sum, 2);
        sq  += __shfl_xor(sq, 1);  sq  += __shfl_xor(sq, 2);
        float mu = sum * (1.f / 128.f);
        float rs = rsqrtf(sq * (1.f / 128.f) - mu * mu + EPS_);
        char* hb = (char*)hA;
        #pragma unroll
        for (int cc = 0; cc < 4; ++cc) {
            short8 pk;
            #pragma unroll
            for (int j = 0; j < 8; ++j) {
                int d0 = q * 32 + cc * 8 + j;
                pk[j] = f2bf((vals[cc*8+j] - mu) * rs * g1[d0] + be1[d0]);
            }
            int byte = (r * 256 + q * 64 + cc * 16) ^ ((r & 7) << 4);
            *(short8*)(hb + byte) = pk;
        }
    }
    __syncthreads();
    int lane = tid & 63, wid = tid >> 6;
    int wm = wid >> 2, wn = wid & 3;  // wave grid 2(M) x 4(N)
    int rlo = lane & 15, khi = lane >> 4;
    f32x4 acc[4][6];
    #pragma unroll
    for (int m = 0; m < 4; ++m)
        #pragma unroll
        for (int n = 0; n < 6; ++n) acc[m][n] = fzero;
    const char* hb = (const char*)hA;
    #pragma unroll
    for (int ks = 0; ks < 4; ++ks) {
        short8 a[4];
        #pragma unroll
        for (int m = 0; m < 4; ++m) {
            int row = (wm * 4 + m) * 16 + rlo;
            int byte = (row * 256 + ks * 64 + khi * 16) ^ ((row & 7) << 4);
            a[m] = *(const short8*)(hb + byte);
        }
        #pragma unroll
        for (int n = 0; n < 6; ++n) {
            int col = (wn * 6 + n) * 16 + rlo;
            short8 bfr = *(const short8*)(WcatT + col * 128 + ks * 32 + khi * 8);
            #pragma unroll
            for (int m = 0; m < 4; ++m) acc[m][n] = mfma16(a[m], bfr, acc[m][n]);
        }
    }
    #pragma unroll
    for (int m = 0; m < 4; ++m) {
        #pragma unroll
        for (int n = 0; n < 6; ++n) {
            int ng = (wn * 6 + n) * 16 + rlo;
            if (ng < 378) {
                int w = ng / 126, r2 = ng % 126;
                int hd = r2 / 21, e = r2 % 21;
                size_t bh = (size_t)b * 6 + hd;
                #pragma unroll
                for (int reg = 0; reg < 4; ++reg) {
                    int t = (wm * 4 + m) * 16 + khi * 4 + reg;
                    short bv = f2bf(acc[m][n][reg]);
                    if (w == 0)      Qg[(bh * 128 + t) * 32 + e] = bv;
                    else if (w == 1) Kg[(bh * 128 + t) * 32 + e] = bv;
                    else             VTg[(bh * 32 + e) * 128 + t] = bv;
                }
            }
        }
    }
}

// ---------------- causal attention per (b,h), all-MFMA ----------------
__global__ __launch_bounds__(256) void attn_kernel(
    const short* __restrict__ Qg, const short* __restrict__ Kg, const short* __restrict__ VTg,
    short* __restrict__ Obf) {
    __shared__ __align__(16) short Qs[T_ * 32];   // [128][32] swz ^((r&3)<<4)
    __shared__ __align__(16) short Ks[T_ * 32];
    __shared__ __align__(16) short VTs[32 * T_];  // [32][128] swz ^((e&7)<<4)
    __shared__ __align__(16) short Ps[T_ * T_];   // [128][128] swz ^((t&7)<<4)
    int h = blockIdx.x, b = blockIdx.y, tid = threadIdx.x;
    size_t bh = (size_t)b * 6 + h;
    const f32x4 fzero = {0.f, 0.f, 0.f, 0.f};
    {
        char* qb = (char*)Qs; char* kb = (char*)Ks;
        const short* Qsrc = Qg + bh * (128 * 32);
        const short* Ksrc = Kg + bh * (128 * 32);
        for (int c = tid; c < 512; c += 256) {
            int r = c >> 2, cc = c & 3;
            int byte = (r * 64 + cc * 16) ^ ((r & 3) << 4);
            short8 qv = {0,0,0,0,0,0,0,0}, kv = {0,0,0,0,0,0,0,0};
            if (cc < 3) {
                qv = *(const short8*)(Qsrc + r * 32 + cc * 8);
                kv = *(const short8*)(Ksrc + r * 32 + cc * 8);
                if (cc == 2) {  // e = 16..23: zero e>=21
                    qv[5] = 0; qv[6] = 0; qv[7] = 0;
                    kv[5] = 0; kv[6] = 0; kv[7] = 0;
                }
            }
            *(short8*)(qb + byte) = qv;
            *(short8*)(kb + byte) = kv;
        }
        char* vb = (char*)VTs;
        const short* Vsrc = VTg + bh * (32 * 128);
        for (int c = tid; c < 512; c += 256) {
            int e = c >> 4, cc = c & 15;
            short8 vv = {0,0,0,0,0,0,0,0};
            if (e < 21) vv = *(const short8*)(Vsrc + e * 128 + cc * 8);
            int byte = (e * 256 + cc * 16) ^ ((e & 7) << 4);
            *(short8*)(vb + byte) = vv;
        }
        short8 z = {0,0,0,0,0,0,0,0};
        char* pb = (char*)Ps;
        for (int c = tid; c < 2048; c += 256) *(short8*)(pb + c * 16) = z;
    }
    __syncthreads();
    int lane = tid & 63, wid = tid >> 6;
    int rlo = lane & 15, khi = lane >> 4;
    const float scale = 0.2182178902359924f;  // 1/sqrt(21)
    const char* qb = (const char*)Qs;
    const char* kb = (const char*)Ks;
    char* pb = (char*)Ps;
    #pragma unroll
    for (int pass = 0; pass < 2; ++pass) {
        int Mt = wid + pass * 4;   // wave-uniform
        int arow = Mt * 16 + rlo;
        short8 a = *(const short8*)(qb + ((arow * 64 + khi * 16) ^ ((arow & 3) << 4)));
        f32x4 sacc[8];
        #pragma unroll
        for (int nt = 0; nt < 8; ++nt) {
            sacc[nt] = fzero;
            if (nt <= Mt) {
                int brow = nt * 16 + rlo;
                short8 bf = *(const short8*)(kb + ((brow * 64 + khi * 16) ^ ((brow & 3) << 4)));
                sacc[nt] = mfma16(a, bf, sacc[nt]);
            }
        }
        #pragma unroll
        for (int reg = 0; reg < 4; ++reg) {
            int t = Mt * 16 + khi * 4 + reg;
            float m = -3e38f;
            #pragma unroll
            for (int nt = 0; nt < 8; ++nt) {
                if (nt <= Mt) {
                    int s = nt * 16 + rlo;
                    float v = (s <= t) ? sacc[nt][reg] * scale : -3e38f;
                    sacc[nt][reg] = v;
                    m = fmaxf(m, v);
                }
            }
            m = fmaxf(m, __shfl_xor(m, 1));
            m = fmaxf(m, __shfl_xor(m, 2));
            m = fmaxf(m, __shfl_xor(m, 4));
            m = fmaxf(m, __shfl_xor(m, 8));
            float sum = 0.f;
            #pragma unroll
            for (int nt = 0; nt < 8; ++nt) {
                if (nt <= Mt) {
                    float p = __expf(sacc[nt][reg] - m);
                    sacc[nt][reg] = p;
                    sum += p;
                }
            }
            sum += __shfl_xor(sum, 1);
            sum += __shfl_xor(sum, 2);
            sum += __shfl_xor(sum, 4);
            sum += __shfl_xor(sum, 8);
            float inv = 1.f / sum;
            #pragma unroll
            for (int nt = 0; nt < 8; ++nt) {
                if (nt <= Mt) {
                    int s = nt * 16 + rlo;
                    int byte = (t * 256 + s * 2) ^ ((t & 7) << 4);
                    *(short*)(pb + byte) = f2bf(sacc[nt][reg] * inv);
                }
            }
        }
    }
    __syncthreads();
    const char* vb = (const char*)VTs;
    #pragma unroll
    for (int pass = 0; pass < 2; ++pass) {
        int Mt = wid + pass * 4;
        f32x4 oacc0 = fzero, oacc1 = fzero;
        int ksmax = Mt >> 1;
        for (int ks = 0; ks <= ksmax; ++ks) {
            int arow = Mt * 16 + rlo;
            int kof = ks * 64 + khi * 16;
            short8 a = *(const short8*)(pb + ((arow * 256 + kof) ^ ((arow & 7) << 4)));
            int er0 = rlo;
            short8 b0 = *(const short8*)(vb + ((er0 * 256 + kof) ^ ((er0 & 7) << 4)));
            oacc0 = mfma16(a, b0, oacc0);
            int er1 = 16 + rlo;
            short8 b1v = *(const short8*)(vb + ((er1 * 256 + kof) ^ ((er1 & 7) << 4)));
            oacc1 = mfma16(a, b1v, oacc1);
        }
        #pragma unroll
        for (int reg = 0; reg < 4; ++reg) {
            int t = Mt * 16 + khi * 4 + reg;
            int e0 = rlo;
            Obf[((size_t)b * 128 + t) * 128 + h * 21 + e0] = f2bf(oacc0[reg]);
            int e1 = 16 + rlo;
            if (e1 < 21)
                Obf[((size_t)b * 128 + t) * 128 + h * 21 + e1] = f2bf(oacc1[reg]);
        }
    }
}

// ---------------- proj: x + o @ Wo + bo -> out (fp32), 64 rows/block ----------------
__global__ __launch_bounds__(256) void proj_kernel(
    const float* __restrict__ x, const short* __restrict__ Obf, const short* __restrict__ WoT,
    const float* __restrict__ bo, float* __restrict__ out) {
    __shared__ __align__(16) short Os[64 * 128];  // swz ^((r&7)<<4)
    int r0 = blockIdx.x * 64, tid = threadIdx.x;
    const f32x4 fzero = {0.f, 0.f, 0.f, 0.f};
    char* ob = (char*)Os;
    for (int c = tid; c < 1024; c += 256) {
        int r = c >> 4, cc = c & 15;
        short8 v = *(const short8*)(Obf + (size_t)(r0 + r) * 128 + cc * 8);
        if (cc == 15) { v[6] = 0; v[7] = 0; }  // cols 126,127 are pad
        int byte = (r * 256 + cc * 16) ^ ((r & 7) << 4);
        *(short8*)(ob + byte) = v;
    }
    __syncthreads();
    int lane = tid & 63, mt = tid >> 6;
    int rlo = lane & 15, khi = lane >> 4;
    #pragma unroll
    for (int nt = 0; nt < 8; ++nt) {
        int d = nt * 16 + rlo;
        f32x4 acc = fzero;
        #pragma unroll
        for (int ks = 0; ks < 4; ++ks) {
            int arow = mt * 16 + rlo;
            short8 a = *(const short8*)(ob + ((arow * 256 + ks * 64 + khi * 16) ^ ((arow & 7) << 4)));
            short8 bf = *(const short8*)(WoT + d * 128 + ks * 32 + khi * 8);
            acc = mfma16(a, bf, acc);
        }
        float bod = bo[d];
        #pragma unroll
        for (int reg = 0; reg < 4; ++reg) {
            int row = r0 + mt * 16 + khi * 4 + reg;
            out[(size_t)row * 128 + d] = x[(size_t)row * 128 + d] + bod + acc[reg];
        }
    }
}

// ---------------- fused LN2 + FF (MFMA) + residual, in place on out ----------------
__global__ __launch_bounds__(256) void ff_kernel(
    float* __restrict__ out, const float* __restrict__ g2, const float* __restrict__ be2,
    const short* __restrict__ W1T, const float* __restrict__ b1,
    const short* __restrict__ W2T, const float* __restrict__ b2) {
    __shared__ __align__(16) short H2[64 * 128];   // swz ^((r&7)<<4)
    __shared__ __align__(16) short FFs[64 * 512];  // swz ^((r&7)<<4), row stride 1024B
    int r0 = blockIdx.x * 64, tid = threadIdx.x;
    const f32x4 fzero = {0.f, 0.f, 0.f, 0.f};
    {   // LN2: 4 threads/row, 64 rows
        int r = tid >> 2, q = tid & 3;
        const float* xr = out + (size_t)(r0 + r) * 128 + q * 32;
        float vals[32];
        float sum = 0.f, sq = 0.f;
        #pragma unroll
        for (int i = 0; i < 8; ++i) {
            f32x4 v4 = *(const f32x4*)(xr + i * 4);
            #pragma unroll
            for (int j = 0; j < 4; ++j) { float vv = v4[j]; vals[i*4+j] = vv; sum += vv; sq += vv*vv; }
        }
        sum += __shfl_xor(sum, 1); sum += __shfl_xor(sum, 2);
        sq  += __shfl_xor(sq, 1);  sq  += __shfl_xor(sq, 2);
        float mu = sum * (1.f / 128.f);
        float rs = rsqrtf(sq * (1.f / 128.f) - mu * mu + EPS_);
        char* hb = (char*)H2;
        #pragma unroll
        for (int cc = 0; cc < 4; ++cc) {
            short8 pk;
            #pragma unroll
            for (int j = 0; j < 8; ++j) {
                int d0 = q * 32 + cc * 8 + j;
                pk[j] = f2bf((vals[cc*8+j] - mu) * rs * g2[d0] + be2[d0]);
            }
            int byte = (r * 256 + q * 64 + cc * 16) ^ ((r & 7) << 4);
            *(short8*)(hb + byte) = pk;
        }
    }
    __syncthreads();
    int lane = tid & 63, mt = tid >> 6;
    int rlo = lane & 15, khi = lane >> 4;
    const char* hb = (const char*)H2;
    char* fb = (char*)FFs;
    for (int nt = 0; nt < 32; ++nt) {
        int j = nt * 16 + rlo;
        f32x4 acc = fzero;
        #pragma unroll
        for (int ks = 0; ks < 4; ++ks) {
            int arow = mt * 16 + rlo;
            short8 a = *(const short8*)(hb + ((arow * 256 + ks * 64 + khi * 16) ^ ((arow & 7) << 4)));
            short8 bf = *(const short8*)(W1T + j * 128 + ks * 32 + khi * 8);
            acc = mfma16(a, bf, acc);
        }
        float b1j = b1[j];
        #pragma unroll
        for (int reg = 0; reg < 4; ++reg) {
            int row = mt * 16 + khi * 4 + reg;
            int byte = (row * 1024 + j * 2) ^ ((row & 7) << 4);
            *(short*)(fb + byte) = f2bf(fmaxf(acc[reg] + b1j, 0.f));
        }
    }
    __syncthreads();
    #pragma unroll
    for (int nt = 0; nt < 8; ++nt) {
        int d = nt * 16 + rlo;
        f32x4 acc = fzero;
        #pragma unroll
        for (int ks = 0; ks < 16; ++ks) {
            int arow = mt * 16 + rlo;
            short8 a = *(const short8*)(fb + ((arow * 1024 + ks * 64 + khi * 16) ^ ((arow & 7) << 4)));
            short8 bf = *(const short8*)(W2T + d * 512 + ks * 32 + khi * 8);
            acc = mfma16(a, bf, acc);
        }
        float b2d = b2[d];
        #pragma unroll
        for (int reg = 0; reg < 4; ++reg) {
            int row = r0 + mt * 16 + khi * 4 + reg;
            size_t gi = (size_t)row * 128 + d;
            out[gi] = out[gi] + b2d + acc[reg];
        }
    }
}

extern "C" void kernel_launch(void* const* d_in, const int* in_sizes, int n_in,
                              void* d_out, int out_size, void* d_ws, size_t ws_size,
                              hipStream_t stream) {
    const float* x   = (const float*)d_in[0];
    const float* Wq  = (const float*)d_in[1];
    const float* Wk  = (const float*)d_in[2];
    const float* Wv  = (const float*)d_in[3];
    const float* Wo  = (const float*)d_in[4];
    const float* bo  = (const float*)d_in[5];
    const float* W1  = (const float*)d_in[6];
    const float* b1  = (const float*)d_in[7];
    const float* W2  = (const float*)d_in[8];
    const float* b2  = (const float*)d_in[9];
    const float* g1  = (const float*)d_in[10];
    const float* be1 = (const float*)d_in[11];
    const float* g2  = (const float*)d_in[12];
    const float* be2 = (const float*)d_in[13];
    float* out = (float*)d_out;

    char* wsb = (char*)d_ws;
    short* WcatT = (short*)(wsb);                 // 98304 B
    short* W1T   = (short*)(wsb + 98304);         // 131072 B
    short* W2T   = (short*)(wsb + 229376);        // 131072 B
    short* WoT   = (short*)(wsb + 360448);        // 32768 B
    short* Qg    = (short*)(wsb + 393216);        // 25165824 B
    short* Kg    = (short*)(wsb + 25559040);      // 25165824 B
    short* VTg   = (short*)(wsb + 50724864);      // 25165824 B
    short* Obf   = (short*)(wsb + 75890688);      // 16777216 B  (total ~92.7 MB)

    prep_kernel<<<768, 256, 0, stream>>>(Wq, Wk, Wv, Wo, W1, W2, WcatT, W1T, W2T, WoT);
    qkv_kernel<<<512, 512, 0, stream>>>(x, g1, be1, WcatT, Qg, Kg, VTg);
    attn_kernel<<<dim3(6, 512), 256, 0, stream>>>(Qg, Kg, VTg, Obf);
    proj_kernel<<<1024, 256, 0, stream>>>(x, Obf, WoT, bo, out);
    ff_kernel<<<1024, 256, 0, stream>>>(out, g2, be2, W1T, b1, W2T, b2);
}

// Round 3
// 360.970 us; speedup vs baseline: 4.3502x; 1.0059x over previous
//
#include <hip/hip_runtime.h>
#include <math.h>

typedef short short8 __attribute__((ext_vector_type(8)));
typedef float f32x4 __attribute__((ext_vector_type(4)));

constexpr int B_ = 512, T_ = 128, D_ = 128, H_ = 6, E_ = 21, DC_ = 126, F_ = 512;
constexpr float EPS_ = 1e-5f;

__device__ __forceinline__ short f2bf(float f) {
    unsigned u = __float_as_uint(f);
    u = (u + 0x7FFFu + ((u >> 16) & 1u)) >> 16;
    return (short)u;
}
__device__ __forceinline__ unsigned pk2(float lo, float hi) {
    return (unsigned)(unsigned short)f2bf(lo) | ((unsigned)(unsigned short)f2bf(hi) << 16);
}
__device__ __forceinline__ f32x4 mfma16(short8 a, short8 b, f32x4 c) {
    return __builtin_amdgcn_mfma_f32_16x16x32_bf16(a, b, c, 0, 0, 0);
}

// ---------------- prep: bf16-cast + transpose all weights into ws ----------------
__global__ __launch_bounds__(256) void prep_kernel(
    const float* __restrict__ Wq, const float* __restrict__ Wk, const float* __restrict__ Wv,
    const float* __restrict__ Wo, const float* __restrict__ W1, const float* __restrict__ W2,
    short* __restrict__ WcatT, short* __restrict__ W1T, short* __restrict__ W2T,
    short* __restrict__ WoT) {
    int idx = blockIdx.x * 256 + threadIdx.x;
    if (idx < 49152) {
        int n = idx >> 7, k = idx & 127;
        float v = 0.f;
        if (n < 378) {
            int w = n / 126, r = n % 126, hd = r / 21, e = r % 21;
            const float* src = (w == 0) ? Wq : (w == 1) ? Wk : Wv;
            v = src[(hd * 128 + k) * 21 + e];
        }
        WcatT[idx] = f2bf(v);
    } else if (idx < 114688) {
        int i = idx - 49152;
        int j = i >> 7, d = i & 127;
        W1T[i] = f2bf(W1[d * 512 + j]);
    } else if (idx < 180224) {
        int i = idx - 114688;
        int d = i >> 9, j = i & 511;
        W2T[i] = f2bf(W2[j * 128 + d]);
    } else if (idx < 196608) {
        int i = idx - 180224;
        int d = i >> 7, c = i & 127;
        WoT[i] = f2bf(c < 126 ? Wo[c * 128 + d] : 0.f);
    }
}

// ---------------- fused LN1 + QKV MFMA: one block per batch b ----------------
__global__ __launch_bounds__(512) void qkv_kernel(
    const float* __restrict__ x, const float* __restrict__ g1, const float* __restrict__ be1,
    const short* __restrict__ WcatT,
    short* __restrict__ Qg, short* __restrict__ Kg, short* __restrict__ VTg) {
    __shared__ __align__(16) short hA[T_ * D_];  // bf16 [128][128], swz ^((row&7)<<4)
    int b = blockIdx.x, tid = threadIdx.x;
    const f32x4 fzero = {0.f, 0.f, 0.f, 0.f};
    {   // LN1: 4 threads per row, 128 rows
        int r = tid >> 2, q = tid & 3;
        const float* xr = x + ((size_t)b * T_ + r) * D_ + q * 32;
        float vals[32];
        float sum = 0.f, sq = 0.f;
        #pragma unroll
        for (int i = 0; i < 8; ++i) {
            f32x4 v4 = *(const f32x4*)(xr + i * 4);
            #pragma unroll
            for (int j = 0; j < 4; ++j) { float vv = v4[j]; vals[i*4+j] = vv; sum += vv; sq += vv*vv; }
        }
        sum += __shfl_xor(sum, 1); sum += __shfl_xor(sum, 2);
        sq  += __shfl_xor(sq, 1);  sq  += __shfl_xor(sq, 2);
        float mu = sum * (1.f / 128.f);
        float rs = rsqrtf(sq * (1.f / 128.f) - mu * mu + EPS_);
        char* hb = (char*)hA;
        #pragma unroll
        for (int cc = 0; cc < 4; ++cc) {
            short8 pk;
            #pragma unroll
            for (int j = 0; j < 8; ++j) {
                int d0 = q * 32 + cc * 8 + j;
                pk[j] = f2bf((vals[cc*8+j] - mu) * rs * g1[d0] + be1[d0]);
            }
            int byte = (r * 256 + q * 64 + cc * 16) ^ ((r & 7) << 4);
            *(short8*)(hb + byte) = pk;
        }
    }
    __syncthreads();
    int lane = tid & 63, wid = tid >> 6;
    int wm = wid >> 2, wn = wid & 3;  // wave grid 2(M) x 4(N)
    int rlo = lane & 15, khi = lane >> 4;
    f32x4 acc[4][6];
    #pragma unroll
    for (int m = 0; m < 4; ++m)
        #pragma unroll
        for (int n = 0; n < 6; ++n) acc[m][n] = fzero;
    const char* hb = (const char*)hA;
    #pragma unroll
    for (int ks = 0; ks < 4; ++ks) {
        short8 a[4];
        #pragma unroll
        for (int m = 0; m < 4; ++m) {
            int row = (wm * 4 + m) * 16 + rlo;
            int byte = (row * 256 + ks * 64 + khi * 16) ^ ((row & 7) << 4);
            a[m] = *(const short8*)(hb + byte);
        }
        #pragma unroll
        for (int n = 0; n < 6; ++n) {
            int col = (wn * 6 + n) * 16 + rlo;
            short8 bfr = *(const short8*)(WcatT + col * 128 + ks * 32 + khi * 8);
            #pragma unroll
            for (int m = 0; m < 4; ++m) acc[m][n] = mfma16(a[m], bfr, acc[m][n]);
        }
    }
    #pragma unroll
    for (int m = 0; m < 4; ++m) {
        #pragma unroll
        for (int n = 0; n < 6; ++n) {
            int ng = (wn * 6 + n) * 16 + rlo;
            if (ng < 378) {
                int w = ng / 126, r2 = ng % 126;
                int hd = r2 / 21, e = r2 % 21;
                size_t bh = (size_t)b * 6 + hd;
                #pragma unroll
                for (int reg = 0; reg < 4; ++reg) {
                    int t = (wm * 4 + m) * 16 + khi * 4 + reg;
                    short bv = f2bf(acc[m][n][reg]);
                    if (w == 0)      Qg[(bh * 128 + t) * 32 + e] = bv;
                    else if (w == 1) Kg[(bh * 128 + t) * 32 + e] = bv;
                    else             VTg[(bh * 32 + e) * 128 + t] = bv;
                }
            }
        }
    }
}

// ---------------- causal attention per (b,h), all-MFMA ----------------
__global__ __launch_bounds__(256) void attn_kernel(
    const short* __restrict__ Qg, const short* __restrict__ Kg, const short* __restrict__ VTg,
    short* __restrict__ Obf) {
    __shared__ __align__(16) short Qs[T_ * 32];   // [128][32] swz ^((r&3)<<4)
    __shared__ __align__(16) short Ks[T_ * 32];
    __shared__ __align__(16) short VTs[32 * T_];  // [32][128] swz ^((e&7)<<4)
    __shared__ __align__(16) short Ps[T_ * T_];   // [128][128] swz ^((t&7)<<4)
    int h = blockIdx.x, b = blockIdx.y, tid = threadIdx.x;
    size_t bh = (size_t)b * 6 + h;
    const f32x4 fzero = {0.f, 0.f, 0.f, 0.f};
    {
        char* qb = (char*)Qs; char* kb = (char*)Ks;
        const short* Qsrc = Qg + bh * (128 * 32);
        const short* Ksrc = Kg + bh * (128 * 32);
        for (int c = tid; c < 512; c += 256) {
            int r = c >> 2, cc = c & 3;
            int byte = (r * 64 + cc * 16) ^ ((r & 3) << 4);
            short8 qv = {0,0,0,0,0,0,0,0}, kv = {0,0,0,0,0,0,0,0};
            if (cc < 3) {
                qv = *(const short8*)(Qsrc + r * 32 + cc * 8);
                kv = *(const short8*)(Ksrc + r * 32 + cc * 8);
                if (cc == 2) {
                    qv[5] = 0; qv[6] = 0; qv[7] = 0;
                    kv[5] = 0; kv[6] = 0; kv[7] = 0;
                }
            }
            *(short8*)(qb + byte) = qv;
            *(short8*)(kb + byte) = kv;
        }
        char* vb = (char*)VTs;
        const short* Vsrc = VTg + bh * (32 * 128);
        for (int c = tid; c < 512; c += 256) {
            int e = c >> 4, cc = c & 15;
            short8 vv = {0,0,0,0,0,0,0,0};
            if (e < 21) vv = *(const short8*)(Vsrc + e * 128 + cc * 8);
            int byte = (e * 256 + cc * 16) ^ ((e & 7) << 4);
            *(short8*)(vb + byte) = vv;
        }
        short8 z = {0,0,0,0,0,0,0,0};
        char* pb = (char*)Ps;
        for (int c = tid; c < 2048; c += 256) *(short8*)(pb + c * 16) = z;
    }
    __syncthreads();
    int lane = tid & 63, wid = tid >> 6;
    int rlo = lane & 15, khi = lane >> 4;
    const float scale = 0.2182178902359924f;  // 1/sqrt(21)
    const char* qb = (const char*)Qs;
    const char* kb = (const char*)Ks;
    char* pb = (char*)Ps;
    #pragma unroll
    for (int pass = 0; pass < 2; ++pass) {
        int Mt = wid + pass * 4;   // wave-uniform
        int arow = Mt * 16 + rlo;
        short8 a = *(const short8*)(qb + ((arow * 64 + khi * 16) ^ ((arow & 3) << 4)));
        f32x4 sacc[8];
        #pragma unroll
        for (int nt = 0; nt < 8; ++nt) {
            sacc[nt] = fzero;
            if (nt <= Mt) {
                int brow = nt * 16 + rlo;
                short8 bf = *(const short8*)(kb + ((brow * 64 + khi * 16) ^ ((brow & 3) << 4)));
                sacc[nt] = mfma16(a, bf, sacc[nt]);
            }
        }
        #pragma unroll
        for (int reg = 0; reg < 4; ++reg) {
            int t = Mt * 16 + khi * 4 + reg;
            float m = -3e38f;
            #pragma unroll
            for (int nt = 0; nt < 8; ++nt) {
                if (nt <= Mt) {
                    int s = nt * 16 + rlo;
                    float v = (s <= t) ? sacc[nt][reg] * scale : -3e38f;
                    sacc[nt][reg] = v;
                    m = fmaxf(m, v);
                }
            }
            m = fmaxf(m, __shfl_xor(m, 1));
            m = fmaxf(m, __shfl_xor(m, 2));
            m = fmaxf(m, __shfl_xor(m, 4));
            m = fmaxf(m, __shfl_xor(m, 8));
            float sum = 0.f;
            #pragma unroll
            for (int nt = 0; nt < 8; ++nt) {
                if (nt <= Mt) {
                    float p = __expf(sacc[nt][reg] - m);
                    sacc[nt][reg] = p;
                    sum += p;
                }
            }
            sum += __shfl_xor(sum, 1);
            sum += __shfl_xor(sum, 2);
            sum += __shfl_xor(sum, 4);
            sum += __shfl_xor(sum, 8);
            float inv = 1.f / sum;
            #pragma unroll
            for (int nt = 0; nt < 8; ++nt) {
                if (nt <= Mt) {
                    int s = nt * 16 + rlo;
                    int byte = (t * 256 + s * 2) ^ ((t & 7) << 4);
                    *(short*)(pb + byte) = f2bf(sacc[nt][reg] * inv);
                }
            }
        }
    }
    __syncthreads();
    const char* vb = (const char*)VTs;
    #pragma unroll
    for (int pass = 0; pass < 2; ++pass) {
        int Mt = wid + pass * 4;
        f32x4 oacc0 = fzero, oacc1 = fzero;
        int ksmax = Mt >> 1;
        for (int ks = 0; ks <= ksmax; ++ks) {
            int arow = Mt * 16 + rlo;
            int kof = ks * 64 + khi * 16;
            short8 a = *(const short8*)(pb + ((arow * 256 + kof) ^ ((arow & 7) << 4)));
            int er0 = rlo;
            short8 b0 = *(const short8*)(vb + ((er0 * 256 + kof) ^ ((er0 & 7) << 4)));
            oacc0 = mfma16(a, b0, oacc0);
            int er1 = 16 + rlo;
            short8 b1v = *(const short8*)(vb + ((er1 * 256 + kof) ^ ((er1 & 7) << 4)));
            oacc1 = mfma16(a, b1v, oacc1);
        }
        #pragma unroll
        for (int reg = 0; reg < 4; ++reg) {
            int t = Mt * 16 + khi * 4 + reg;
            int e0 = rlo;
            Obf[((size_t)b * 128 + t) * 128 + h * 21 + e0] = f2bf(oacc0[reg]);
            int e1 = 16 + rlo;
            if (e1 < 21)
                Obf[((size_t)b * 128 + t) * 128 + h * 21 + e1] = f2bf(oacc1[reg]);
        }
    }
}

// ---------------- proj: x + o @ Wo + bo -> out (fp32), 64 rows/block ----------------
__global__ __launch_bounds__(256) void proj_kernel(
    const float* __restrict__ x, const short* __restrict__ Obf, const short* __restrict__ WoT,
    const float* __restrict__ bo, float* __restrict__ out) {
    __shared__ __align__(16) short Os[64 * 128];  // swz ^((r&7)<<4)
    int r0 = blockIdx.x * 64, tid = threadIdx.x;
    const f32x4 fzero = {0.f, 0.f, 0.f, 0.f};
    char* ob = (char*)Os;
    for (int c = tid; c < 1024; c += 256) {
        int r = c >> 4, cc = c & 15;
        short8 v = *(const short8*)(Obf + (size_t)(r0 + r) * 128 + cc * 8);
        if (cc == 15) { v[6] = 0; v[7] = 0; }
        int byte = (r * 256 + cc * 16) ^ ((r & 7) << 4);
        *(short8*)(ob + byte) = v;
    }
    __syncthreads();
    int lane = tid & 63, mt = tid >> 6;
    int rlo = lane & 15, khi = lane >> 4;
    #pragma unroll
    for (int nt = 0; nt < 8; ++nt) {
        int d = nt * 16 + rlo;
        f32x4 acc = fzero;
        #pragma unroll
        for (int ks = 0; ks < 4; ++ks) {
            int arow = mt * 16 + rlo;
            short8 a = *(const short8*)(ob + ((arow * 256 + ks * 64 + khi * 16) ^ ((arow & 7) << 4)));
            short8 bf = *(const short8*)(WoT + d * 128 + ks * 32 + khi * 8);
            acc = mfma16(a, bf, acc);
        }
        float bod = bo[d];
        #pragma unroll
        for (int reg = 0; reg < 4; ++reg) {
            int row = r0 + mt * 16 + khi * 4 + reg;
            out[(size_t)row * 128 + d] = x[(size_t)row * 128 + d] + bod + acc[reg];
        }
    }
}

// ---------------- fused LN2 + FF, all in registers per wave ----------------
// Block = 256 threads = 4 waves; each wave owns 16 rows end-to-end.
// FF1 computed SWAPPED (A=W1T rows j, B=H rows t) so acc holds F^T with j on the
// reg-dim; 8 shfl + 4 selects rebuild the FF2 A-fragment (row t, k=j) in-register.
// LDS: 4 KiB per wave (H tile staging for LN->fragment redistribution) = 16 KiB.
__global__ __launch_bounds__(256) void ff_kernel(
    float* __restrict__ out, const float* __restrict__ g2, const float* __restrict__ be2,
    const short* __restrict__ W1T, const float* __restrict__ b1,
    const short* __restrict__ W2T, const float* __restrict__ b2) {
    __shared__ __align__(16) short Hs[4 * 16 * 128];  // per-wave [16][128] bf16, swz ^((r&7)<<4)
    int tid = threadIdx.x;
    int lane = tid & 63, wid = tid >> 6;
    int rlo = lane & 15, khi = lane >> 4;
    int rowbase = blockIdx.x * 64 + wid * 16;
    const f32x4 fzero = {0.f, 0.f, 0.f, 0.f};
    {   // LN2: 4 lanes per row over this wave's 16 rows
        int rl = lane >> 2, q = lane & 3;
        const float* xr = out + (size_t)(blockIdx.x * 64 + wid * 16 + rl) * D_ + q * 32;
        float vals[32];
        float sum = 0.f, sq = 0.f;
        #pragma unroll
        for (int i = 0; i < 8; ++i) {
            f32x4 v4 = *(const f32x4*)(xr + i * 4);
            #pragma unroll
            for (int j = 0; j < 4; ++j) { float vv = v4[j]; vals[i*4+j] = vv; sum += vv; sq += vv*vv; }
        }
        sum += __shfl_xor(sum, 1); sum += __shfl_xor(sum, 2);
        sq  += __shfl_xor(sq, 1);  sq  += __shfl_xor(sq, 2);
        float mu = sum * (1.f / 128.f);
        float rs = rsqrtf(sq * (1.f / 128.f) - mu * mu + EPS_);
        char* hb = (char*)Hs + wid * 4096;
        #pragma unroll
        for (int cc = 0; cc < 4; ++cc) {
            short8 pk;
            #pragma unroll
            for (int j = 0; j < 8; ++j) {
                int d0 = q * 32 + cc * 8 + j;
                pk[j] = f2bf((vals[cc*8+j] - mu) * rs * g2[d0] + be2[d0]);
            }
            int byte = (rl * 256 + q * 64 + cc * 16) ^ ((rl & 7) << 4);
            *(short8*)(hb + byte) = pk;
        }
    }
    __syncthreads();
    // H fragments: row rlo, k = kk*32 + khi*8 .. +7
    short8 hfrag[4];
    {
        const char* hb = (const char*)Hs + wid * 4096;
        #pragma unroll
        for (int kk = 0; kk < 4; ++kk)
            hfrag[kk] = *(const short8*)(hb + ((rlo * 256 + kk * 64 + khi * 16) ^ ((rlo & 7) << 4)));
    }
    f32x4 oacc[8];
    #pragma unroll
    for (int n = 0; n < 8; ++n) oacc[n] = fzero;
    int sl0 = rlo + (khi & 1) * 32, sl1 = sl0 + 16;
    bool upper = (khi >> 1) != 0;
    for (int ks = 0; ks < 16; ++ks) {
        int jA = ks * 32, jB = ks * 32 + 16;
        f32x4 accA = fzero, accB = fzero;
        #pragma unroll
        for (int kk = 0; kk < 4; ++kk) {
            short8 wa = *(const short8*)(W1T + (size_t)(jA + rlo) * 128 + kk * 32 + khi * 8);
            short8 wb = *(const short8*)(W1T + (size_t)(jB + rlo) * 128 + kk * 32 + khi * 8);
            accA = mfma16(wa, hfrag[kk], accA);
            accB = mfma16(wb, hfrag[kk], accB);
        }
        // bias + relu; per lane j = jA/jB + khi*4 + reg
        f32x4 bqA = *(const f32x4*)(b1 + jA + khi * 4);
        f32x4 bqB = *(const f32x4*)(b1 + jB + khi * 4);
        float a0 = fmaxf(accA[0] + bqA[0], 0.f), a1 = fmaxf(accA[1] + bqA[1], 0.f);
        float a2 = fmaxf(accA[2] + bqA[2], 0.f), a3 = fmaxf(accA[3] + bqA[3], 0.f);
        float c0 = fmaxf(accB[0] + bqB[0], 0.f), c1 = fmaxf(accB[1] + bqB[1], 0.f);
        float c2 = fmaxf(accB[2] + bqB[2], 0.f), c3 = fmaxf(accB[3] + bqB[3], 0.f);
        unsigned wA0 = pk2(a0, a1), wA1 = pk2(a2, a3);
        unsigned wB0 = pk2(c0, c1), wB1 = pk2(c2, c3);
        // route F^T words -> FF2 A-fragment (row t = rlo, k = ks*32 + khi*8 + 0..7)
        unsigned a00 = __shfl(wA0, sl0), a01 = __shfl(wA1, sl0);
        unsigned a10 = __shfl(wA0, sl1), a11 = __shfl(wA1, sl1);
        unsigned c00 = __shfl(wB0, sl0), c01 = __shfl(wB1, sl0);
        unsigned c10 = __shfl(wB0, sl1), c11 = __shfl(wB1, sl1);
        union { unsigned u[4]; short8 s; } ffu;
        ffu.u[0] = upper ? c00 : a00;
        ffu.u[1] = upper ? c01 : a01;
        ffu.u[2] = upper ? c10 : a10;
        ffu.u[3] = upper ? c11 : a11;
        #pragma unroll
        for (int ndt = 0; ndt < 8; ++ndt) {
            short8 w2 = *(const short8*)(W2T + (size_t)(ndt * 16 + rlo) * 512 + ks * 32 + khi * 8);
            oacc[ndt] = mfma16(ffu.s, w2, oacc[ndt]);
        }
    }
    // epilogue: out += b2 + FF2
    #pragma unroll
    for (int ndt = 0; ndt < 8; ++ndt) {
        int d = ndt * 16 + rlo;
        float b2d = b2[d];
        #pragma unroll
        for (int reg = 0; reg < 4; ++reg) {
            int row = rowbase + khi * 4 + reg;
            size_t gi = (size_t)row * D_ + d;
            out[gi] = out[gi] + b2d + oacc[ndt][reg];
        }
    }
}

extern "C" void kernel_launch(void* const* d_in, const int* in_sizes, int n_in,
                              void* d_out, int out_size, void* d_ws, size_t ws_size,
                              hipStream_t stream) {
    const float* x   = (const float*)d_in[0];
    const float* Wq  = (const float*)d_in[1];
    const float* Wk  = (const float*)d_in[2];
    const float* Wv  = (const float*)d_in[3];
    const float* Wo  = (const float*)d_in[4];
    const float* bo  = (const float*)d_in[5];
    const float* W1  = (const float*)d_in[6];
    const float* b1  = (const float*)d_in[7];
    const float* W2  = (const float*)d_in[8];
    const float* b2  = (const float*)d_in[9];
    const float* g1  = (const float*)d_in[10];
    const float* be1 = (const float*)d_in[11];
    const float* g2  = (const float*)d_in[12];
    const float* be2 = (const float*)d_in[13];
    float* out = (float*)d_out;

    char* wsb = (char*)d_ws;
    short* WcatT = (short*)(wsb);                 // 98304 B
    short* W1T   = (short*)(wsb + 98304);         // 131072 B
    short* W2T   = (short*)(wsb + 229376);        // 131072 B
    short* WoT   = (short*)(wsb + 360448);        // 32768 B
    short* Qg    = (short*)(wsb + 393216);
    short* Kg    = (short*)(wsb + 25559040);
    short* VTg   = (short*)(wsb + 50724864);
    short* Obf   = (short*)(wsb + 75890688);      // total ~92.7 MB

    prep_kernel<<<768, 256, 0, stream>>>(Wq, Wk, Wv, Wo, W1, W2, WcatT, W1T, W2T, WoT);
    qkv_kernel<<<512, 512, 0, stream>>>(x, g1, be1, WcatT, Qg, Kg, VTg);
    attn_kernel<<<dim3(6, 512), 256, 0, stream>>>(Qg, Kg, VTg, Obf);
    proj_kernel<<<1024, 256, 0, stream>>>(x, Obf, WoT, bo, out);
    ff_kernel<<<1024, 256, 0, stream>>>(out, g2, be2, W1T, b1, W2T, b2);
}

// Round 4
// 278.111 us; speedup vs baseline: 5.6463x; 1.2979x over previous
//
#include <hip/hip_runtime.h>
#include <math.h>

typedef short short8 __attribute__((ext_vector_type(8)));
typedef float f32x4 __attribute__((ext_vector_type(4)));

constexpr int B_ = 512, T_ = 128, D_ = 128, H_ = 6, E_ = 21, DC_ = 126, F_ = 512;
constexpr float EPS_ = 1e-5f;

__device__ __forceinline__ short f2bf(float f) {
    unsigned u = __float_as_uint(f);
    u = (u + 0x7FFFu + ((u >> 16) & 1u)) >> 16;
    return (short)u;
}
__device__ __forceinline__ unsigned pk2(float lo, float hi) {
    return (unsigned)(unsigned short)f2bf(lo) | ((unsigned)(unsigned short)f2bf(hi) << 16);
}
__device__ __forceinline__ f32x4 mfma16(short8 a, short8 b, f32x4 c) {
    return __builtin_amdgcn_mfma_f32_16x16x32_bf16(a, b, c, 0, 0, 0);
}

// ---------------- prep: bf16-cast + transpose all weights into ws ----------------
__global__ __launch_bounds__(256) void prep_kernel(
    const float* __restrict__ Wq, const float* __restrict__ Wk, const float* __restrict__ Wv,
    const float* __restrict__ Wo, const float* __restrict__ W1, const float* __restrict__ W2,
    short* __restrict__ WcatT, short* __restrict__ W1T, short* __restrict__ W2T,
    short* __restrict__ WoT) {
    int idx = blockIdx.x * 256 + threadIdx.x;
    if (idx < 49152) {
        int n = idx >> 7, k = idx & 127;
        float v = 0.f;
        if (n < 378) {
            int w = n / 126, r = n % 126, hd = r / 21, e = r % 21;
            const float* src = (w == 0) ? Wq : (w == 1) ? Wk : Wv;
            v = src[(hd * 128 + k) * 21 + e];
        }
        WcatT[idx] = f2bf(v);
    } else if (idx < 114688) {
        int i = idx - 49152;
        int j = i >> 7, d = i & 127;
        W1T[i] = f2bf(W1[d * 512 + j]);
    } else if (idx < 180224) {
        int i = idx - 114688;
        int d = i >> 9, j = i & 511;
        W2T[i] = f2bf(W2[j * 128 + d]);
    } else if (idx < 196608) {
        int i = idx - 180224;
        int d = i >> 7, c = i & 127;
        WoT[i] = f2bf(c < 126 ? Wo[c * 128 + d] : 0.f);
    }
}

// ---------------- fused LN1 + QKV MFMA: one block per batch b ----------------
__global__ __launch_bounds__(512) void qkv_kernel(
    const float* __restrict__ x, const float* __restrict__ g1, const float* __restrict__ be1,
    const short* __restrict__ WcatT,
    short* __restrict__ Qg, short* __restrict__ Kg, short* __restrict__ VTg) {
    __shared__ __align__(16) short hA[T_ * D_];  // bf16 [128][128], swz ^((row&7)<<4)
    int b = blockIdx.x, tid = threadIdx.x;
    const f32x4 fzero = {0.f, 0.f, 0.f, 0.f};
    {   // LN1: 4 threads per row, 128 rows
        int r = tid >> 2, q = tid & 3;
        const float* xr = x + ((size_t)b * T_ + r) * D_ + q * 32;
        float vals[32];
        float sum = 0.f, sq = 0.f;
        #pragma unroll
        for (int i = 0; i < 8; ++i) {
            f32x4 v4 = *(const f32x4*)(xr + i * 4);
            #pragma unroll
            for (int j = 0; j < 4; ++j) { float vv = v4[j]; vals[i*4+j] = vv; sum += vv; sq += vv*vv; }
        }
        sum += __shfl_xor(sum, 1); sum += __shfl_xor(sum, 2);
        sq  += __shfl_xor(sq, 1);  sq  += __shfl_xor(sq, 2);
        float mu = sum * (1.f / 128.f);
        float rs = rsqrtf(sq * (1.f / 128.f) - mu * mu + EPS_);
        char* hb = (char*)hA;
        #pragma unroll
        for (int cc = 0; cc < 4; ++cc) {
            short8 pk;
            #pragma unroll
            for (int j = 0; j < 8; ++j) {
                int d0 = q * 32 + cc * 8 + j;
                pk[j] = f2bf((vals[cc*8+j] - mu) * rs * g1[d0] + be1[d0]);
            }
            int byte = (r * 256 + q * 64 + cc * 16) ^ ((r & 7) << 4);
            *(short8*)(hb + byte) = pk;
        }
    }
    __syncthreads();
    int lane = tid & 63, wid = tid >> 6;
    int wm = wid >> 2, wn = wid & 3;  // wave grid 2(M) x 4(N)
    int rlo = lane & 15, khi = lane >> 4;
    f32x4 acc[4][6];
    #pragma unroll
    for (int m = 0; m < 4; ++m)
        #pragma unroll
        for (int n = 0; n < 6; ++n) acc[m][n] = fzero;
    const char* hb = (const char*)hA;
    #pragma unroll
    for (int ks = 0; ks < 4; ++ks) {
        short8 a[4];
        #pragma unroll
        for (int m = 0; m < 4; ++m) {
            int row = (wm * 4 + m) * 16 + rlo;
            int byte = (row * 256 + ks * 64 + khi * 16) ^ ((row & 7) << 4);
            a[m] = *(const short8*)(hb + byte);
        }
        #pragma unroll
        for (int n = 0; n < 6; ++n) {
            int col = (wn * 6 + n) * 16 + rlo;
            short8 bfr = *(const short8*)(WcatT + col * 128 + ks * 32 + khi * 8);
            #pragma unroll
            for (int m = 0; m < 4; ++m) acc[m][n] = mfma16(a[m], bfr, acc[m][n]);
        }
    }
    #pragma unroll
    for (int m = 0; m < 4; ++m) {
        #pragma unroll
        for (int n = 0; n < 6; ++n) {
            int ng = (wn * 6 + n) * 16 + rlo;
            if (ng < 378) {
                int w = ng / 126, r2 = ng % 126;
                int hd = r2 / 21, e = r2 % 21;
                size_t bh = (size_t)b * 6 + hd;
                #pragma unroll
                for (int reg = 0; reg < 4; ++reg) {
                    int t = (wm * 4 + m) * 16 + khi * 4 + reg;
                    short bv = f2bf(acc[m][n][reg]);
                    if (w == 0)      Qg[(bh * 128 + t) * 32 + e] = bv;
                    else if (w == 1) Kg[(bh * 128 + t) * 32 + e] = bv;
                    else             VTg[(bh * 32 + e) * 128 + t] = bv;
                }
            }
        }
    }
}

// ---------------- causal attention per (b,h), all-MFMA ----------------
__global__ __launch_bounds__(256) void attn_kernel(
    const short* __restrict__ Qg, const short* __restrict__ Kg, const short* __restrict__ VTg,
    short* __restrict__ Obf) {
    __shared__ __align__(16) short Qs[T_ * 32];   // [128][32] swz ^((r&3)<<4)
    __shared__ __align__(16) short Ks[T_ * 32];
    __shared__ __align__(16) short VTs[32 * T_];  // [32][128] swz ^((e&7)<<4)
    __shared__ __align__(16) short Ps[T_ * T_];   // [128][128] swz ^((t&7)<<4)
    int h = blockIdx.x, b = blockIdx.y, tid = threadIdx.x;
    size_t bh = (size_t)b * 6 + h;
    const f32x4 fzero = {0.f, 0.f, 0.f, 0.f};
    {
        char* qb = (char*)Qs; char* kb = (char*)Ks;
        const short* Qsrc = Qg + bh * (128 * 32);
        const short* Ksrc = Kg + bh * (128 * 32);
        for (int c = tid; c < 512; c += 256) {
            int r = c >> 2, cc = c & 3;
            int byte = (r * 64 + cc * 16) ^ ((r & 3) << 4);
            short8 qv = {0,0,0,0,0,0,0,0}, kv = {0,0,0,0,0,0,0,0};
            if (cc < 3) {
                qv = *(const short8*)(Qsrc + r * 32 + cc * 8);
                kv = *(const short8*)(Ksrc + r * 32 + cc * 8);
                if (cc == 2) {
                    qv[5] = 0; qv[6] = 0; qv[7] = 0;
                    kv[5] = 0; kv[6] = 0; kv[7] = 0;
                }
            }
            *(short8*)(qb + byte) = qv;
            *(short8*)(kb + byte) = kv;
        }
        char* vb = (char*)VTs;
        const short* Vsrc = VTg + bh * (32 * 128);
        for (int c = tid; c < 512; c += 256) {
            int e = c >> 4, cc = c & 15;
            short8 vv = {0,0,0,0,0,0,0,0};
            if (e < 21) vv = *(const short8*)(Vsrc + e * 128 + cc * 8);
            int byte = (e * 256 + cc * 16) ^ ((e & 7) << 4);
            *(short8*)(vb + byte) = vv;
        }
        short8 z = {0,0,0,0,0,0,0,0};
        char* pb = (char*)Ps;
        for (int c = tid; c < 2048; c += 256) *(short8*)(pb + c * 16) = z;
    }
    __syncthreads();
    int lane = tid & 63, wid = tid >> 6;
    int rlo = lane & 15, khi = lane >> 4;
    const float scale = 0.2182178902359924f;  // 1/sqrt(21)
    const char* qb = (const char*)Qs;
    const char* kb = (const char*)Ks;
    char* pb = (char*)Ps;
    #pragma unroll
    for (int pass = 0; pass < 2; ++pass) {
        int Mt = wid + pass * 4;   // wave-uniform
        int arow = Mt * 16 + rlo;
        short8 a = *(const short8*)(qb + ((arow * 64 + khi * 16) ^ ((arow & 3) << 4)));
        f32x4 sacc[8];
        #pragma unroll
        for (int nt = 0; nt < 8; ++nt) {
            sacc[nt] = fzero;
            if (nt <= Mt) {
                int brow = nt * 16 + rlo;
                short8 bf = *(const short8*)(kb + ((brow * 64 + khi * 16) ^ ((brow & 3) << 4)));
                sacc[nt] = mfma16(a, bf, sacc[nt]);
            }
        }
        #pragma unroll
        for (int reg = 0; reg < 4; ++reg) {
            int t = Mt * 16 + khi * 4 + reg;
            float m = -3e38f;
            #pragma unroll
            for (int nt = 0; nt < 8; ++nt) {
                if (nt <= Mt) {
                    int s = nt * 16 + rlo;
                    float v = (s <= t) ? sacc[nt][reg] * scale : -3e38f;
                    sacc[nt][reg] = v;
                    m = fmaxf(m, v);
                }
            }
            m = fmaxf(m, __shfl_xor(m, 1));
            m = fmaxf(m, __shfl_xor(m, 2));
            m = fmaxf(m, __shfl_xor(m, 4));
            m = fmaxf(m, __shfl_xor(m, 8));
            float sum = 0.f;
            #pragma unroll
            for (int nt = 0; nt < 8; ++nt) {
                if (nt <= Mt) {
                    float p = __expf(sacc[nt][reg] - m);
                    sacc[nt][reg] = p;
                    sum += p;
                }
            }
            sum += __shfl_xor(sum, 1);
            sum += __shfl_xor(sum, 2);
            sum += __shfl_xor(sum, 4);
            sum += __shfl_xor(sum, 8);
            float inv = 1.f / sum;
            #pragma unroll
            for (int nt = 0; nt < 8; ++nt) {
                if (nt <= Mt) {
                    int s = nt * 16 + rlo;
                    int byte = (t * 256 + s * 2) ^ ((t & 7) << 4);
                    *(short*)(pb + byte) = f2bf(sacc[nt][reg] * inv);
                }
            }
        }
    }
    __syncthreads();
    const char* vb = (const char*)VTs;
    #pragma unroll
    for (int pass = 0; pass < 2; ++pass) {
        int Mt = wid + pass * 4;
        f32x4 oacc0 = fzero, oacc1 = fzero;
        int ksmax = Mt >> 1;
        for (int ks = 0; ks <= ksmax; ++ks) {
            int arow = Mt * 16 + rlo;
            int kof = ks * 64 + khi * 16;
            short8 a = *(const short8*)(pb + ((arow * 256 + kof) ^ ((arow & 7) << 4)));
            int er0 = rlo;
            short8 b0 = *(const short8*)(vb + ((er0 * 256 + kof) ^ ((er0 & 7) << 4)));
            oacc0 = mfma16(a, b0, oacc0);
            int er1 = 16 + rlo;
            short8 b1v = *(const short8*)(vb + ((er1 * 256 + kof) ^ ((er1 & 7) << 4)));
            oacc1 = mfma16(a, b1v, oacc1);
        }
        #pragma unroll
        for (int reg = 0; reg < 4; ++reg) {
            int t = Mt * 16 + khi * 4 + reg;
            int e0 = rlo;
            Obf[((size_t)b * 128 + t) * 128 + h * 21 + e0] = f2bf(oacc0[reg]);
            int e1 = 16 + rlo;
            if (e1 < 21)
                Obf[((size_t)b * 128 + t) * 128 + h * 21 + e1] = f2bf(oacc1[reg]);
        }
    }
}

// ---------------- proj: x + o @ Wo + bo -> out (fp32), 64 rows/block ----------------
__global__ __launch_bounds__(256) void proj_kernel(
    const float* __restrict__ x, const short* __restrict__ Obf, const short* __restrict__ WoT,
    const float* __restrict__ bo, float* __restrict__ out) {
    __shared__ __align__(16) short Os[64 * 128];  // swz ^((r&7)<<4)
    int r0 = blockIdx.x * 64, tid = threadIdx.x;
    const f32x4 fzero = {0.f, 0.f, 0.f, 0.f};
    char* ob = (char*)Os;
    for (int c = tid; c < 1024; c += 256) {
        int r = c >> 4, cc = c & 15;
        short8 v = *(const short8*)(Obf + (size_t)(r0 + r) * 128 + cc * 8);
        if (cc == 15) { v[6] = 0; v[7] = 0; }
        int byte = (r * 256 + cc * 16) ^ ((r & 7) << 4);
        *(short8*)(ob + byte) = v;
    }
    __syncthreads();
    int lane = tid & 63, mt = tid >> 6;
    int rlo = lane & 15, khi = lane >> 4;
    #pragma unroll
    for (int nt = 0; nt < 8; ++nt) {
        int d = nt * 16 + rlo;
        f32x4 acc = fzero;
        #pragma unroll
        for (int ks = 0; ks < 4; ++ks) {
            int arow = mt * 16 + rlo;
            short8 a = *(const short8*)(ob + ((arow * 256 + ks * 64 + khi * 16) ^ ((arow & 7) << 4)));
            short8 bf = *(const short8*)(WoT + d * 128 + ks * 32 + khi * 8);
            acc = mfma16(a, bf, acc);
        }
        float bod = bo[d];
        #pragma unroll
        for (int reg = 0; reg < 4; ++reg) {
            int row = r0 + mt * 16 + khi * 4 + reg;
            out[(size_t)row * 128 + d] = x[(size_t)row * 128 + d] + bod + acc[reg];
        }
    }
}

// ---------------- fused LN2 + FF v2: wave-split weights, F through LDS ----------------
// Block = 256 thr = 4 waves, 64 rows. Wave wid: FF1 for j in [wid*128, wid*128+128)
// over all 64 rows (swapped MFMA, W1T rows read once per block -> 32KB/wave);
// packed bf16 F^T -> LDS Fs [64 t][512 j] (swz). Barrier. FF2: wave wid computes
// d in [wid*32, wid*32+32) over all 64 rows; A-frags from LDS, W2T 32KB/wave.
// Weight L2 traffic: 256KB/block (was 1MB/wave). Global loads/wave: 64 (was 256).
__global__ __launch_bounds__(256, 2) void ff_kernel(
    float* __restrict__ out, const float* __restrict__ g2, const float* __restrict__ be2,
    const short* __restrict__ W1T, const float* __restrict__ b1,
    const short* __restrict__ W2T, const float* __restrict__ b2) {
    __shared__ __align__(16) short Hs[64 * 128];  // 16KB, row stride 256B, swz ^((r&7)<<4)
    __shared__ __align__(16) short Fs[64 * 512];  // 64KB, row stride 1024B, swz ^((t&7)<<4)
    int tid = threadIdx.x;
    int lane = tid & 63, wid = tid >> 6;
    int rlo = lane & 15, khi = lane >> 4;
    int rowbase = blockIdx.x * 64;
    const f32x4 fzero = {0.f, 0.f, 0.f, 0.f};
    {   // LN2: wave wid handles rows wid*16..+15; 4 lanes per row
        int rl = lane >> 2, q = lane & 3;
        int r = wid * 16 + rl;
        const float* xr = out + (size_t)(rowbase + r) * D_ + q * 32;
        float vals[32];
        float sum = 0.f, sq = 0.f;
        #pragma unroll
        for (int i = 0; i < 8; ++i) {
            f32x4 v4 = *(const f32x4*)(xr + i * 4);
            #pragma unroll
            for (int j = 0; j < 4; ++j) { float vv = v4[j]; vals[i*4+j] = vv; sum += vv; sq += vv*vv; }
        }
        sum += __shfl_xor(sum, 1); sum += __shfl_xor(sum, 2);
        sq  += __shfl_xor(sq, 1);  sq  += __shfl_xor(sq, 2);
        float mu = sum * (1.f / 128.f);
        float rs = rsqrtf(sq * (1.f / 128.f) - mu * mu + EPS_);
        char* hb = (char*)Hs;
        #pragma unroll
        for (int cc = 0; cc < 4; ++cc) {
            short8 pk;
            #pragma unroll
            for (int j = 0; j < 8; ++j) {
                int d0 = q * 32 + cc * 8 + j;
                pk[j] = f2bf((vals[cc*8+j] - mu) * rs * g2[d0] + be2[d0]);
            }
            int byte = (r * 256 + q * 64 + cc * 16) ^ ((r & 7) << 4);
            *(short8*)(hb + byte) = pk;
        }
    }
    __syncthreads();
    // H B-fragments for all 4 row-tiles (kept in registers: 64 VGPR)
    short8 hfr[4][4];  // [mt][kk]: rows t=mt*16+rlo, k=kk*32+khi*8
    {
        const char* hb = (const char*)Hs;
        #pragma unroll
        for (int mt = 0; mt < 4; ++mt)
            #pragma unroll
            for (int kk = 0; kk < 4; ++kk) {
                int t = mt * 16 + rlo;
                hfr[mt][kk] = *(const short8*)(hb + ((t * 256 + kk * 64 + khi * 16) ^ ((t & 7) << 4)));
            }
    }
    // FF1: swapped MFMA, j-split by wave
    {
        const short* W1w = W1T + (size_t)(wid * 128) * 128;
        char* fb = (char*)Fs;
        #pragma unroll 2
        for (int jt = 0; jt < 8; ++jt) {
            f32x4 fa[4];
            #pragma unroll
            for (int mt = 0; mt < 4; ++mt) fa[mt] = fzero;
            #pragma unroll
            for (int kk = 0; kk < 4; ++kk) {
                short8 wa = *(const short8*)(W1w + (size_t)(jt * 16 + rlo) * 128 + kk * 32 + khi * 8);
                #pragma unroll
                for (int mt = 0; mt < 4; ++mt) fa[mt] = mfma16(wa, hfr[mt][kk], fa[mt]);
            }
            // j = wid*128 + jt*16 + khi*4 + reg ; t = mt*16 + rlo
            f32x4 bq = *(const f32x4*)(b1 + wid * 128 + jt * 16 + khi * 4);
            #pragma unroll
            for (int mt = 0; mt < 4; ++mt) {
                float v0 = fmaxf(fa[mt][0] + bq[0], 0.f);
                float v1 = fmaxf(fa[mt][1] + bq[1], 0.f);
                float v2 = fmaxf(fa[mt][2] + bq[2], 0.f);
                float v3 = fmaxf(fa[mt][3] + bq[3], 0.f);
                uint2 w;
                w.x = pk2(v0, v1);
                w.y = pk2(v2, v3);
                int t = mt * 16 + rlo;
                int byte = (t * 1024 + wid * 256 + jt * 32 + khi * 8) ^ ((t & 7) << 4);
                *(uint2*)(fb + byte) = w;
            }
        }
    }
    __syncthreads();
    // FF2: d-split by wave; A from LDS Fs, B = W2T rows d (32KB/wave)
    f32x4 oa[4][2];
    #pragma unroll
    for (int mt = 0; mt < 4; ++mt) { oa[mt][0] = fzero; oa[mt][1] = fzero; }
    {
        const char* fb = (const char*)Fs;
        const short* W2w = W2T + (size_t)(wid * 32) * 512;
        #pragma unroll 4
        for (int ks = 0; ks < 16; ++ks) {
            short8 af[4];
            #pragma unroll
            for (int mt = 0; mt < 4; ++mt) {
                int t = mt * 16 + rlo;
                af[mt] = *(const short8*)(fb + ((t * 1024 + ks * 64 + khi * 16) ^ ((t & 7) << 4)));
            }
            #pragma unroll
            for (int nd = 0; nd < 2; ++nd) {
                short8 wf = *(const short8*)(W2w + (size_t)(nd * 16 + rlo) * 512 + ks * 32 + khi * 8);
                #pragma unroll
                for (int mt = 0; mt < 4; ++mt) oa[mt][nd] = mfma16(af[mt], wf, oa[mt][nd]);
            }
        }
    }
    // epilogue: out += b2 + FF2  (rows: all 64; cols: this wave's 32)
    #pragma unroll
    for (int nd = 0; nd < 2; ++nd) {
        int d = wid * 32 + nd * 16 + rlo;
        float b2d = b2[d];
        #pragma unroll
        for (int mt = 0; mt < 4; ++mt) {
            #pragma unroll
            for (int reg = 0; reg < 4; ++reg) {
                int row = rowbase + mt * 16 + khi * 4 + reg;
                size_t gi = (size_t)row * D_ + d;
                out[gi] = out[gi] + b2d + oa[mt][nd][reg];
            }
        }
    }
}

extern "C" void kernel_launch(void* const* d_in, const int* in_sizes, int n_in,
                              void* d_out, int out_size, void* d_ws, size_t ws_size,
                              hipStream_t stream) {
    const float* x   = (const float*)d_in[0];
    const float* Wq  = (const float*)d_in[1];
    const float* Wk  = (const float*)d_in[2];
    const float* Wv  = (const float*)d_in[3];
    const float* Wo  = (const float*)d_in[4];
    const float* bo  = (const float*)d_in[5];
    const float* W1  = (const float*)d_in[6];
    const float* b1  = (const float*)d_in[7];
    const float* W2  = (const float*)d_in[8];
    const float* b2  = (const float*)d_in[9];
    const float* g1  = (const float*)d_in[10];
    const float* be1 = (const float*)d_in[11];
    const float* g2  = (const float*)d_in[12];
    const float* be2 = (const float*)d_in[13];
    float* out = (float*)d_out;

    char* wsb = (char*)d_ws;
    short* WcatT = (short*)(wsb);                 // 98304 B
    short* W1T   = (short*)(wsb + 98304);         // 131072 B
    short* W2T   = (short*)(wsb + 229376);        // 131072 B
    short* WoT   = (short*)(wsb + 360448);        // 32768 B
    short* Qg    = (short*)(wsb + 393216);
    short* Kg    = (short*)(wsb + 25559040);
    short* VTg   = (short*)(wsb + 50724864);
    short* Obf   = (short*)(wsb + 75890688);      // total ~92.7 MB

    prep_kernel<<<768, 256, 0, stream>>>(Wq, Wk, Wv, Wo, W1, W2, WcatT, W1T, W2T, WoT);
    qkv_kernel<<<512, 512, 0, stream>>>(x, g1, be1, WcatT, Qg, Kg, VTg);
    attn_kernel<<<dim3(6, 512), 256, 0, stream>>>(Qg, Kg, VTg, Obf);
    proj_kernel<<<1024, 256, 0, stream>>>(x, Obf, WoT, bo, out);
    ff_kernel<<<1024, 256, 0, stream>>>(out, g2, be2, W1T, b1, W2T, b2);
}